// Round 9
// baseline (41.147 us; speedup 1.0000x reference)
//
#include <hip/hip_runtime.h>
#include <math.h>

#define HP 65   // padded histogram row (kills stride-64 bank conflicts)

__device__ __forceinline__ float clip1000(float v) {
  return fminf(fmaxf(v, -1000.0f), 1000.0f);
}

// Shared MLP slice: lane l of a 16-lane group computes hidden units [8l,8l+8),
// then a 4-step shfl tree reduces. ONE copy (noinline) shared by every heavy
// call site -> identical features give bit-identical z (tie semantics kept).
__device__ __noinline__ float mlp16(const float* sw, float f0, float f1, float f2, int l) {
  const float* w1a = sw;        const float* w1b = sw + 128;
  const float* w1c = sw + 256;  const float* b1v = sw + 384;
  const float* w2v = sw + 512;
  float zp = 0.0f;
  {
    #pragma clang fp contract(off)
    #pragma unroll
    for (int k = l * 8; k < l * 8 + 8; ++k) {
      float pre = f0 * w1a[k] + f1 * w1b[k] + f2 * w1c[k] + b1v[k];
      float e = erff(pre / (float)M_SQRT2);
      float hg = 0.5f * pre * (1.0f + e);   // exact GELU
      zp = zp + hg * w2v[k];
    }
  }
  zp += __shfl_xor(zp, 1);
  zp += __shfl_xor(zp, 2);
  zp += __shfl_xor(zp, 4);
  zp += __shfl_xor(zp, 8);
  return zp;
}

// Exact np.argmax (first max) across one 64-lane wave; invalid lanes pass
// -3.0e9f. Returns lowest lane index holding the max.
__device__ __forceinline__ int firstmax64(float z) {
  float m = z;
  m = fmaxf(m, __shfl_xor(m, 1));
  m = fmaxf(m, __shfl_xor(m, 2));
  m = fmaxf(m, __shfl_xor(m, 4));
  m = fmaxf(m, __shfl_xor(m, 8));
  m = fmaxf(m, __shfl_xor(m, 16));
  m = fmaxf(m, __shfl_xor(m, 32));
  return (int)__builtin_ctzll(__ballot(z == m));
}

__launch_bounds__(1024, 1)
__global__ void sim_kernel(const int* __restrict__ tables,
                           const int* __restrict__ sigma,
                           const int* __restrict__ x,
                           const int* __restrict__ base_obs,
                           const float* __restrict__ W1,
                           const float* __restrict__ b1,
                           const float* __restrict__ W2,
                           const float* __restrict__ b2,
                           const int* __restrict__ max_steps_p,
                           float* __restrict__ out,
                           int B, int V, int N)
{
  const int b = blockIdx.x;
  const int tid = threadIdx.x;
  const int T = max_steps_p[0];

  __shared__ unsigned short s_pos[8192];   // candidate positions (in-place compacted)
  __shared__ int s_gidx[8192];             // global indices of initial set
  __shared__ int s_lab[256 * 33];          // label cache [pos][view] (if cached)
  __shared__ int s_h[32 * HP];             // histograms (single buffer)
  __shared__ float s_w[641];               // W1(384) b1(128) W2(128) b2(1)
  __shared__ float s_z[33];
  __shared__ float s_zc[6];                // precomputed tail z constants
  __shared__ int s_used[32], s_ycnt[32], s_resp[32];
  __shared__ int s_nact, s_cnt, s_a, s_r;

  const int* tb = tables + (size_t)b * V * N;
  const int* sg = sigma + (size_t)b * N;
  const int bo = base_obs[b];
  const int xb = x[b];

  // ---------------- INIT: pure LDS, no global loads ----------------
  #pragma clang loop unroll(disable)
  for (int i = tid; i < 32 * HP; i += 1024) s_h[i] = 0;
  if (tid < 32) { s_used[tid] = 0; s_ycnt[tid] = 0; }
  if (tid == 0) s_nact = 0;
  __syncthreads();

  // ---------------- PAR: scan (tid<896) | resp (896..927) | weights+tail-z (wave 15) ----------------
  if (tid < 896) {
    const int4* tb4 = (const int4*)tb;
    #pragma clang loop unroll(disable)
    for (int q = tid; q < (N >> 2); q += 896) {
      int4 v4 = tb4[q]; int base = q << 2;
      if (v4.x == bo) { int p = atomicAdd(&s_nact, 1); s_gidx[p] = base; }
      if (v4.y == bo) { int p = atomicAdd(&s_nact, 1); s_gidx[p] = base + 1; }
      if (v4.z == bo) { int p = atomicAdd(&s_nact, 1); s_gidx[p] = base + 2; }
      if (v4.w == bo) { int p = atomicAdd(&s_nact, 1); s_gidx[p] = base + 3; }
    }
  } else if (tid < 928) {
    s_resp[tid - 896] = tb[(size_t)(tid - 896) * N + xb];
  } else if (tid >= 960) {
    const int lane = tid - 960;
    // stage all weights with one wave (in-order DS deps within a wave)
    #pragma clang loop unroll(disable)
    for (int k = lane; k < 641; k += 64) {
      float wv;
      if (k < 384) wv = W1[k];
      else if (k < 512) wv = b1[k - 384];
      else if (k < 640) wv = W2[k - 512];
      else wv = b2[0];
      s_w[k] = wv;
    }
    // 6 tail-z constants: 8-lane groups, SAME code for all 6 -> exact ties
    // among constants (tail never compares these against heavy-path z).
    const int g = lane >> 3, l = lane & 7;
    const float zcf[6][3] = {
      {1.0f, 1.0f, 2.0f},       // A: view, es=2
      {0.0f, 0.0f, 1.0f},       // B: view es=1; stop(closed,total=1)
      {1000.0f, 0.0f, 1.0f},    // C: view0, es0=1
      {1000.0f, 1.0f, 2.0f},    // D: view0 es0=2; stop(open,total=2)
      {0.0f, -1.0f, 0.0f},      // E: view, nact=0
      {1000.0f, -1.0f, 0.0f}};  // F: view0, nact=0
    if (g < 6) {
      const float f0 = zcf[g][0], f1 = zcf[g][1], f2 = zcf[g][2];
      float zp = 0.0f;
      {
        #pragma clang fp contract(off)
        #pragma unroll
        for (int k = l * 16; k < l * 16 + 16; ++k) {
          float pre = f0 * s_w[k] + f1 * s_w[128 + k] + f2 * s_w[256 + k] + s_w[384 + k];
          float e = erff(pre / (float)M_SQRT2);
          float hg = 0.5f * pre * (1.0f + e);
          zp = zp + hg * s_w[512 + k];
        }
      }
      zp += __shfl_xor(zp, 1);
      zp += __shfl_xor(zp, 2);
      zp += __shfl_xor(zp, 4);
      if (l == 0) s_zc[g] = zp + s_w[640];
    }
  }
  __syncthreads();

  const int nact0 = s_nact;
  const bool cached = (nact0 <= 256);
  const int v32 = tid >> 5, g32 = tid & 31;

  auto labelOf = [&](int pos, int vv) -> int {
    return cached ? s_lab[pos * 33 + vv] : tb[(size_t)vv * N + s_gidx[pos]];
  };

  // ---------------- phase B: batched one-shot gather + cache + initial hist ----------------
  {
    const int* row = tb + (size_t)v32 * N;
    if (cached) {
      int labs[8];
      #pragma unroll
      for (int u = 0; u < 8; ++u) {           // all scattered loads in flight first
        int j = g32 + (u << 5);
        if (j < nact0) labs[u] = row[s_gidx[j]];
      }
      #pragma unroll
      for (int u = 0; u < 8; ++u) {
        int j = g32 + (u << 5);
        if (j < nact0) {
          s_lab[j * 33 + v32] = labs[u];
          atomicAdd(&s_h[v32 * HP + labs[u]], 1);
        }
      }
    } else {
      #pragma clang loop unroll(disable)
      for (int j = g32; j < nact0; j += 32)
        atomicAdd(&s_h[v32 * HP + row[s_gidx[j]]], 1);
    }
    #pragma clang loop unroll(disable)
    for (int j = tid; j < nact0; j += 1024) s_pos[j] = (unsigned short)j;
  }
  __syncthreads();

  // ---------------- heavy loop (nact > 2) ----------------
  int t = 0, a = -1, r = 0;
  bool stopped = false, tail = false;
  while (t < T) {
    const int nact = s_nact;
    if (nact <= 2) { tail = true; break; }

    // ---- PH1: features + MLP (33 groups x 16 lanes) from s_h ----
    if (tid < 528) {
      const int view = tid >> 4, l = tid & 15;
      const float total = (float)nact;
      float f0, f1, f2;
      if (view == 32) {
        f0 = 1000.0f;                    // open (total>1)
        f1 = clip1000(total - 1.0f);
        f2 = clip1000(total);
      } else {
        long long sumsq = 0;
        #pragma unroll
        for (int o = l * 4; o < l * 4 + 4; ++o) {
          long long c = (long long)s_h[view * HP + o];
          sumsq += c * c;
        }
        sumsq += __shfl_xor(sumsq, 1);
        sumsq += __shfl_xor(sumsq, 2);
        sumsq += __shfl_xor(sumsq, 4);
        sumsq += __shfl_xor(sumsq, 8);
        float es = (float)sumsq / total;
        float steps = (view == 0) ? 1000.0f : log2f(fmaxf(es, 1.0f));
        f0 = clip1000(steps); f1 = clip1000(es - 1.0f); f2 = clip1000(es);
      }
      float zp = mlp16(s_w, f0, f1, f2, l);
      if (l == 0) s_z[view] = zp + s_w[640];
    }
    __syncthreads();

    // ---- PH2: wave-parallel first-max argmax + exact integer chain;
    //      threads 64+ zero s_h for the (possible) next histogram ----
    if (tid < 64) {
      float z = (tid < 33) ? s_z[tid] : -3.0e9f;
      int jstar = firstmax64(z);
      unsigned usedm;
      { bool ub = (tid < 32) && (s_used[tid] != 0);
        usedm = (unsigned)__ballot(ub); }
      int aa;
      if (jstar == 32 || (jstar >= 1 && !((usedm >> jstar) & 1u))) aa = jstar;
      else {
        unsigned freeb = ~usedm & 0x7ffffffeu;   // views 1..31 unused
        aa = freeb ? (int)__builtin_ctz(freeb) : 32;
      }
      if (tid == 0) {
        int rr = 0;
        if (aa != 32) { s_used[aa] = 1; rr = s_resp[aa]; }
        s_a = aa; s_r = rr; s_cnt = 0;
        out[b * T + t] = (float)aa;
        out[(size_t)B * T + b * T + t] = (float)rr;
      }
    } else {
      #pragma clang loop unroll(disable)
      for (int i = tid - 64; i < 32 * HP; i += 960) s_h[i] = 0;
    }
    __syncthreads();

    a = s_a; r = s_r;
    ++t;
    if (a == 32) { stopped = true; break; }

    // ---- FILTER: group-a's half-wave compacts s_pos in place.
    //      Chunk reads are register-batched before any write (lockstep). ----
    if (v32 == a) {
      for (int c0 = 0; c0 < nact; c0 += 256) {
        int poss[8], keep[8];
        #pragma unroll
        for (int u = 0; u < 8; ++u) {
          int j = c0 + g32 + (u << 5);
          poss[u] = (j < nact) ? (int)s_pos[j] : 0;
          keep[u] = (j < nact) && (labelOf(poss[u], a) == r);
        }
        #pragma unroll
        for (int u = 0; u < 8; ++u) {
          if (keep[u]) { int p = atomicAdd(&s_cnt, 1); s_pos[p] = (unsigned short)poss[u]; }
        }
      }
      if (g32 == 0) s_nact = s_cnt;
    }
    __syncthreads();

    // ---- HIST over survivors, only if another heavy step will read it ----
    const int newn = s_nact;
    if (t < T && newn > 2) {
      #pragma clang loop unroll(disable)
      for (int idx = tid; idx < newn * 32; idx += 1024) {
        int j = idx >> 5, v = idx & 31;
        atomicAdd(&s_h[v * HP + labelOf(s_pos[j], v)], 1);
      }
      __syncthreads();
    }
  }

  if (tail) {
    // ---------------- single-wave tail (nact <= 2) + inline y epilogue ----------------
    if (tid < 64) {
      const int lane = tid;
      int nact = s_nact;
      int p0 = (nact >= 1) ? (int)s_pos[0] : 0;
      int p1 = (nact == 2) ? (int)s_pos[1] : 0;
      // prefetch sigma of the (at most 2) possible survivors; latency hides
      // under the tail loop. Track whether p0 later becomes the old p1.
      int sva = 0, svb = 0; bool swapped = false;
      if (nact >= 1) sva = sg[s_gidx[p0]];
      if (nact == 2) svb = sg[s_gidx[p1]];
      unsigned usedmask;
      { bool ub = (lane < 32) && (s_used[lane] != 0);
        usedmask = (unsigned)__ballot(ub); }
      const float zA = s_zc[0], zB = s_zc[1], zC = s_zc[2],
                  zD = s_zc[3], zE = s_zc[4], zF = s_zc[5];
      unsigned esmask = 0;
      if (nact == 2) {
        int l0 = (lane < 32) ? labelOf(p0, lane) : 0;
        int l1 = (lane < 32) ? labelOf(p1, lane) : 0;
        esmask = (unsigned)__ballot(lane < 32 && (l0 == l1));
      }

      #pragma clang loop unroll(disable)
      for (; t < T; ++t) {
        // lane i<32 holds view-i z; lane 32 holds stop z; others -3e9
        float zi;
        if (nact == 2) {
          if (lane == 0)       zi = (esmask & 1u) ? zD : zC;
          else if (lane < 32)  zi = ((esmask >> lane) & 1u) ? zA : zB;
          else if (lane == 32) zi = zD;                      // stop(open,total=2)
          else zi = -3.0e9f;
        } else if (nact == 1) {
          zi = (lane == 0) ? zC : (lane <= 32) ? zB : -3.0e9f;  // stop(closed)==zB
        } else {
          if (lane == 0)       zi = zF;
          else if (lane < 32)  zi = zE;
          else if (lane == 32) zi = zB;                      // stop(closed,total=1)
          else zi = -3.0e9f;
        }
        int jstar = firstmax64(zi);
        int a2;
        if (jstar == 32 || (jstar >= 1 && !((usedmask >> jstar) & 1u))) a2 = jstar;
        else {
          unsigned freeb = ~usedmask & 0x7ffffffeu;          // views 1..31 unused
          a2 = freeb ? (int)__builtin_ctz(freeb) : 32;
        }
        if (a2 == 32) {
          if (lane == 0) {
            #pragma clang loop unroll(disable)
            for (int tt = t; tt < T; ++tt) {
              out[b * T + tt] = (float)V;
              out[(size_t)B * T + b * T + tt] = 0.0f;
            }
          }
          break;
        }
        usedmask |= (1u << a2);
        int r2 = s_resp[a2];
        if (lane == 0) {
          out[b * T + t] = (float)a2;
          out[(size_t)B * T + b * T + t] = (float)r2;
        }
        if (nact == 2) {
          bool k0 = (labelOf(p0, a2) == r2);
          bool k1 = (labelOf(p1, a2) == r2);
          if (k0 && k1) { /* pair intact: esmask stays valid */ }
          else if (k0) { nact = 1; }
          else if (k1) { nact = 1; p0 = p1; swapped = true; }
          else { nact = 0; }
        } else if (nact == 1) {
          if (labelOf(p0, a2) != r2) nact = 0;
        }
      }
      // inline y_logits: survivors subset of the 2 prefetched candidates
      if (lane < 32) {
        float q = 1.0f / (float)(nact > 1 ? nact : 1);
        int cnt = 0;
        if (nact == 2)      cnt = (sva == lane) + (svb == lane);
        else if (nact == 1) cnt = ((swapped ? svb : sva) == lane);
        float p = (cnt == 2) ? (q + q) : (cnt == 1 ? q : 0.0f);  // doubling exact
        out[(size_t)2 * B * T + b * 32 + lane] = logf(fmaxf(p, 1e-9f));
      }
    }
  } else {
    // ---------------- rare path: stopped early or T exhausted with nact>2 ----------------
    if (stopped && tid == 0) {
      #pragma clang loop unroll(disable)
      for (int tt = t; tt < T; ++tt) {
        out[b * T + tt] = (float)V;
        out[(size_t)B * T + b * T + tt] = 0.0f;
      }
    }
    const int nfin = s_nact;
    #pragma clang loop unroll(disable)
    for (int j = tid; j < nfin; j += 1024) {
      atomicAdd(&s_ycnt[sg[s_gidx[s_pos[j]]]], 1);
    }
    __syncthreads();
    if (tid < 32) {
      float denom = (float)(nfin > 1 ? nfin : 1);
      float q = 1.0f / denom;
      int c = s_ycnt[tid];
      float p = 0.0f;
      #pragma clang loop unroll(disable)
      for (int k = 0; k < c; ++k) p = p + q;  // fl-adds of equal values == scatter-add
      out[(size_t)2 * B * T + b * 32 + tid] = logf(fmaxf(p, 1e-9f));
    }
  }
}

extern "C" void kernel_launch(void* const* d_in, const int* in_sizes, int n_in,
                              void* d_out, int out_size, void* d_ws, size_t ws_size,
                              hipStream_t stream) {
  const int* tables   = (const int*)d_in[0];
  const int* sigma    = (const int*)d_in[1];
  const int* x        = (const int*)d_in[2];
  const int* base_obs = (const int*)d_in[3];
  const float* W1 = (const float*)d_in[4];
  const float* b1 = (const float*)d_in[5];
  const float* W2 = (const float*)d_in[6];
  const float* b2 = (const float*)d_in[7];
  const int* msteps = (const int*)d_in[8];
  float* out = (float*)d_out;

  const int B = in_sizes[2];
  const int N = in_sizes[1] / B;
  const int V = in_sizes[0] / (B * N);

  sim_kernel<<<dim3(B), dim3(1024), 0, stream>>>(
      tables, sigma, x, base_obs, W1, b1, W2, b2, msteps, out, B, V, N);
}

// Round 10
// 36.905 us; speedup vs baseline: 1.1149x; 1.1149x over previous
//
#include <hip/hip_runtime.h>
#include <math.h>

#define HP 65   // padded histogram row (kills stride-64 bank conflicts)

__device__ __forceinline__ float clip1000(float v) {
  return fminf(fmaxf(v, -1000.0f), 1000.0f);
}

// Shared MLP slice: lane l of a 16-lane group computes hidden units [8l,8l+8),
// then a 4-step shfl tree reduces. ONE copy (noinline) shared by every call
// site -> identical features give bit-identical z (tie semantics preserved).
__device__ __noinline__ float mlp16(const float* sw, float f0, float f1, float f2, int l) {
  const float* w1a = sw;        const float* w1b = sw + 128;
  const float* w1c = sw + 256;  const float* b1v = sw + 384;
  const float* w2v = sw + 512;
  float zp = 0.0f;
  {
    #pragma clang fp contract(off)
    #pragma unroll
    for (int k = l * 8; k < l * 8 + 8; ++k) {
      float pre = f0 * w1a[k] + f1 * w1b[k] + f2 * w1c[k] + b1v[k];
      float e = erff(pre / (float)M_SQRT2);
      float hg = 0.5f * pre * (1.0f + e);   // exact GELU
      zp = zp + hg * w2v[k];
    }
  }
  zp += __shfl_xor(zp, 1);
  zp += __shfl_xor(zp, 2);
  zp += __shfl_xor(zp, 4);
  zp += __shfl_xor(zp, 8);
  return zp;
}

// Exact np.argmax (first max) across one 64-lane wave; invalid lanes pass
// -3.0e9f. Returns lowest lane index holding the max.
__device__ __forceinline__ int firstmax64(float z) {
  float m = z;
  m = fmaxf(m, __shfl_xor(m, 1));
  m = fmaxf(m, __shfl_xor(m, 2));
  m = fmaxf(m, __shfl_xor(m, 4));
  m = fmaxf(m, __shfl_xor(m, 8));
  m = fmaxf(m, __shfl_xor(m, 16));
  m = fmaxf(m, __shfl_xor(m, 32));
  return (int)__builtin_ctzll(__ballot(z == m));
}

__launch_bounds__(1024, 1)
__global__ void sim_kernel(const int* __restrict__ tables,
                           const int* __restrict__ sigma,
                           const int* __restrict__ x,
                           const int* __restrict__ base_obs,
                           const float* __restrict__ W1,
                           const float* __restrict__ b1,
                           const float* __restrict__ W2,
                           const float* __restrict__ b2,
                           const int* __restrict__ max_steps_p,
                           float* __restrict__ out,
                           int B, int V, int N)
{
  const int b = blockIdx.x;
  const int tid = threadIdx.x;
  const int T = max_steps_p[0];

  __shared__ unsigned short s_pos[8192];   // candidate positions (in-place compacted)
  __shared__ int s_gidx[8192];             // global indices of initial set
  __shared__ int s_lab[256 * 33];          // label cache [pos][view] (if cached)
  __shared__ int s_h[32 * HP];             // histograms (single buffer)
  __shared__ float s_w[641];               // W1(384) b1(128) W2(128) b2(1)
  __shared__ float s_z[33];
  __shared__ float s_zc[6];                // precomputed tail z constants
  __shared__ int s_used[32], s_ycnt[32], s_resp[32];
  __shared__ int s_nact, s_cnt, s_a, s_r;

  const int* tb = tables + (size_t)b * V * N;
  const int* sg = sigma + (size_t)b * N;
  const int bo = base_obs[b];
  const int xb = x[b];

  // ---------------- phase A: stage weights/responses (parallel), zero, init ----------------
  {
    float wv = 0.0f;
    if (tid < 384) wv = W1[tid];
    else if (tid < 512) wv = b1[tid - 384];
    else if (tid < 640) wv = W2[tid - 512];
    else if (tid == 640) wv = b2[0];
    if (tid <= 640) s_w[tid] = wv;
  }
  if (tid >= 704 && tid < 736) s_resp[tid - 704] = tb[(size_t)(tid - 704) * N + xb];
  #pragma clang loop unroll(disable)
  for (int i = tid; i < 32 * HP; i += 1024) s_h[i] = 0;
  if (tid < 32) { s_used[tid] = 0; s_ycnt[tid] = 0; }
  if (tid == 0) s_nact = 0;
  __syncthreads();

  // ---------------- SCAN: m0 (tid<928) + tail-z constants (tid>=928) ----------------
  if (tid < 928) {
    const int4* tb4 = (const int4*)tb;
    #pragma clang loop unroll(disable)
    for (int q = tid; q < (N >> 2); q += 928) {
      int4 v4 = tb4[q]; int base = q << 2;
      if (v4.x == bo) { int p = atomicAdd(&s_nact, 1); s_gidx[p] = base; }
      if (v4.y == bo) { int p = atomicAdd(&s_nact, 1); s_gidx[p] = base + 1; }
      if (v4.z == bo) { int p = atomicAdd(&s_nact, 1); s_gidx[p] = base + 2; }
      if (v4.w == bo) { int p = atomicAdd(&s_nact, 1); s_gidx[p] = base + 3; }
    }
  } else {
    // Only feature vectors reachable when nact<=2 (6 distinct).
    const int g = (tid - 928) >> 4, l = (tid - 928) & 15;
    const float zcf[6][3] = {
      {1.0f, 1.0f, 2.0f},       // A: view, es=2
      {0.0f, 0.0f, 1.0f},       // B: view es=1; stop(closed,total=1)
      {1000.0f, 0.0f, 1.0f},    // C: view0, es0=1
      {1000.0f, 1.0f, 2.0f},    // D: view0 es0=2; stop(open,total=2)
      {0.0f, -1.0f, 0.0f},      // E: view, nact=0
      {1000.0f, -1.0f, 0.0f}};  // F: view0, nact=0
    if (g < 6) {
      float zp = mlp16(s_w, zcf[g][0], zcf[g][1], zcf[g][2], l);
      if (l == 0) s_zc[g] = zp + s_w[640];
    }
  }
  __syncthreads();

  const int nact0 = s_nact;
  const bool cached = (nact0 <= 256);
  const int v32 = tid >> 5, g32 = tid & 31;

  auto labelOf = [&](int pos, int vv) -> int {
    return cached ? s_lab[pos * 33 + vv] : tb[(size_t)vv * N + s_gidx[pos]];
  };

  // ---------------- phase B: batched one-shot gather + cache + initial hist ----------------
  {
    const int* row = tb + (size_t)v32 * N;
    if (cached) {
      int labs[8];
      #pragma unroll
      for (int u = 0; u < 8; ++u) {           // all scattered loads in flight first
        int j = g32 + (u << 5);
        if (j < nact0) labs[u] = row[s_gidx[j]];
      }
      #pragma unroll
      for (int u = 0; u < 8; ++u) {
        int j = g32 + (u << 5);
        if (j < nact0) {
          s_lab[j * 33 + v32] = labs[u];
          atomicAdd(&s_h[v32 * HP + labs[u]], 1);
        }
      }
    } else {
      #pragma clang loop unroll(disable)
      for (int j = g32; j < nact0; j += 32)
        atomicAdd(&s_h[v32 * HP + row[s_gidx[j]]], 1);
    }
    #pragma clang loop unroll(disable)
    for (int j = tid; j < nact0; j += 1024) s_pos[j] = (unsigned short)j;
  }
  __syncthreads();

  // ---------------- heavy loop (nact > 2) ----------------
  int t = 0, a = -1, r = 0;
  bool stopped = false, tail = false;
  while (t < T) {
    const int nact = s_nact;
    if (nact <= 2) { tail = true; break; }

    // ---- PH1: features + MLP (33 groups x 16 lanes) from s_h ----
    if (tid < 528) {
      const int view = tid >> 4, l = tid & 15;
      const float total = (float)nact;
      float f0, f1, f2;
      if (view == 32) {
        f0 = 1000.0f;                    // open (total>1)
        f1 = clip1000(total - 1.0f);
        f2 = clip1000(total);
      } else {
        long long sumsq = 0;
        #pragma unroll
        for (int o = l * 4; o < l * 4 + 4; ++o) {
          long long c = (long long)s_h[view * HP + o];
          sumsq += c * c;
        }
        sumsq += __shfl_xor(sumsq, 1);
        sumsq += __shfl_xor(sumsq, 2);
        sumsq += __shfl_xor(sumsq, 4);
        sumsq += __shfl_xor(sumsq, 8);
        float es = (float)sumsq / total;
        float steps = (view == 0) ? 1000.0f : log2f(fmaxf(es, 1.0f));
        f0 = clip1000(steps); f1 = clip1000(es - 1.0f); f2 = clip1000(es);
      }
      float zp = mlp16(s_w, f0, f1, f2, l);
      if (l == 0) s_z[view] = zp + s_w[640];
    }
    __syncthreads();

    // ---- PH2: wave-parallel first-max argmax + exact integer chain;
    //      threads 64+ zero s_h for the (possible) next histogram ----
    if (tid < 64) {
      float z = (tid < 33) ? s_z[tid] : -3.0e9f;
      int jstar = firstmax64(z);
      unsigned usedm;
      { bool ub = (tid < 32) && (s_used[tid] != 0);
        usedm = (unsigned)__ballot(ub); }
      int aa;
      if (jstar == 32 || (jstar >= 1 && !((usedm >> jstar) & 1u))) aa = jstar;
      else {
        unsigned freeb = ~usedm & 0x7ffffffeu;   // views 1..31 unused
        aa = freeb ? (int)__builtin_ctz(freeb) : 32;
      }
      if (tid == 0) {
        int rr = 0;
        if (aa != 32) { s_used[aa] = 1; rr = s_resp[aa]; }
        s_a = aa; s_r = rr; s_cnt = 0;
        out[b * T + t] = (float)aa;
        out[(size_t)B * T + b * T + t] = (float)rr;
      }
    } else {
      #pragma clang loop unroll(disable)
      for (int i = tid - 64; i < 32 * HP; i += 960) s_h[i] = 0;
    }
    __syncthreads();

    a = s_a; r = s_r;
    ++t;
    if (a == 32) { stopped = true; break; }

    // ---- FILTER: group-a's half-wave compacts s_pos in place.
    //      Chunk reads are register-batched before any write (lockstep). ----
    if (v32 == a) {
      for (int c0 = 0; c0 < nact; c0 += 256) {
        int poss[8], keep[8];
        #pragma unroll
        for (int u = 0; u < 8; ++u) {
          int j = c0 + g32 + (u << 5);
          poss[u] = (j < nact) ? (int)s_pos[j] : 0;
          keep[u] = (j < nact) && (labelOf(poss[u], a) == r);
        }
        #pragma unroll
        for (int u = 0; u < 8; ++u) {
          if (keep[u]) { int p = atomicAdd(&s_cnt, 1); s_pos[p] = (unsigned short)poss[u]; }
        }
      }
      if (g32 == 0) s_nact = s_cnt;
    }
    __syncthreads();

    // ---- HIST over survivors, only if another heavy step will read it ----
    const int newn = s_nact;
    if (t < T && newn > 2) {
      #pragma clang loop unroll(disable)
      for (int idx = tid; idx < newn * 32; idx += 1024) {
        int j = idx >> 5, v = idx & 31;
        atomicAdd(&s_h[v * HP + labelOf(s_pos[j], v)], 1);
      }
      __syncthreads();
    }
  }

  if (tail) {
    // ---------------- single-wave tail (nact <= 2) + inline y epilogue ----------------
    if (tid < 64) {
      const int lane = tid;
      int nact = s_nact;
      int p0 = (nact >= 1) ? (int)s_pos[0] : 0;
      int p1 = (nact == 2) ? (int)s_pos[1] : 0;
      // prefetch sigma of the (at most 2) possible survivors; latency hides
      // under the tail loop. Track whether p0 later becomes the old p1.
      int sva = 0, svb = 0; bool swapped = false;
      if (nact >= 1) sva = sg[s_gidx[p0]];
      if (nact == 2) svb = sg[s_gidx[p1]];
      unsigned usedmask;
      { bool ub = (lane < 32) && (s_used[lane] != 0);
        usedmask = (unsigned)__ballot(ub); }
      const float zA = s_zc[0], zB = s_zc[1], zC = s_zc[2],
                  zD = s_zc[3], zE = s_zc[4], zF = s_zc[5];
      unsigned esmask = 0;
      if (nact == 2) {
        int l0 = (lane < 32) ? labelOf(p0, lane) : 0;
        int l1 = (lane < 32) ? labelOf(p1, lane) : 0;
        esmask = (unsigned)__ballot(lane < 32 && (l0 == l1));
      }

      #pragma clang loop unroll(disable)
      for (; t < T; ++t) {
        // lane i<32 holds view-i z; lane 32 holds stop z; others -3e9
        float zi;
        if (nact == 2) {
          if (lane == 0)       zi = (esmask & 1u) ? zD : zC;
          else if (lane < 32)  zi = ((esmask >> lane) & 1u) ? zA : zB;
          else if (lane == 32) zi = zD;                      // stop(open,total=2)
          else zi = -3.0e9f;
        } else if (nact == 1) {
          zi = (lane == 0) ? zC : (lane <= 32) ? zB : -3.0e9f;  // stop(closed)==zB
        } else {
          if (lane == 0)       zi = zF;
          else if (lane < 32)  zi = zE;
          else if (lane == 32) zi = zB;                      // stop(closed,total=1)
          else zi = -3.0e9f;
        }
        int jstar = firstmax64(zi);
        int a2;
        if (jstar == 32 || (jstar >= 1 && !((usedmask >> jstar) & 1u))) a2 = jstar;
        else {
          unsigned freeb = ~usedmask & 0x7ffffffeu;          // views 1..31 unused
          a2 = freeb ? (int)__builtin_ctz(freeb) : 32;
        }
        if (a2 == 32) {
          if (lane == 0) {
            #pragma clang loop unroll(disable)
            for (int tt = t; tt < T; ++tt) {
              out[b * T + tt] = (float)V;
              out[(size_t)B * T + b * T + tt] = 0.0f;
            }
          }
          break;
        }
        usedmask |= (1u << a2);
        int r2 = s_resp[a2];
        if (lane == 0) {
          out[b * T + t] = (float)a2;
          out[(size_t)B * T + b * T + t] = (float)r2;
        }
        if (nact == 2) {
          bool k0 = (labelOf(p0, a2) == r2);
          bool k1 = (labelOf(p1, a2) == r2);
          if (k0 && k1) { /* pair intact: esmask stays valid */ }
          else if (k0) { nact = 1; }
          else if (k1) { nact = 1; p0 = p1; swapped = true; }
          else { nact = 0; }
        } else if (nact == 1) {
          if (labelOf(p0, a2) != r2) nact = 0;
        }
      }
      // inline y_logits: survivors are a subset of the 2 prefetched candidates
      if (lane < 32) {
        float q = 1.0f / (float)(nact > 1 ? nact : 1);
        int cnt = 0;
        if (nact == 2)      cnt = (sva == lane) + (svb == lane);
        else if (nact == 1) cnt = ((swapped ? svb : sva) == lane);
        float p = (cnt == 2) ? (q + q) : (cnt == 1 ? q : 0.0f);  // doubling exact
        out[(size_t)2 * B * T + b * 32 + lane] = logf(fmaxf(p, 1e-9f));
      }
    }
  } else {
    // ---------------- rare path: stopped early or T exhausted with nact>2 ----------------
    if (stopped && tid == 0) {
      #pragma clang loop unroll(disable)
      for (int tt = t; tt < T; ++tt) {
        out[b * T + tt] = (float)V;
        out[(size_t)B * T + b * T + tt] = 0.0f;
      }
    }
    const int nfin = s_nact;
    #pragma clang loop unroll(disable)
    for (int j = tid; j < nfin; j += 1024) {
      atomicAdd(&s_ycnt[sg[s_gidx[s_pos[j]]]], 1);
    }
    __syncthreads();
    if (tid < 32) {
      float denom = (float)(nfin > 1 ? nfin : 1);
      float q = 1.0f / denom;
      int c = s_ycnt[tid];
      float p = 0.0f;
      #pragma clang loop unroll(disable)
      for (int k = 0; k < c; ++k) p = p + q;  // fl-adds of equal values == scatter-add
      out[(size_t)2 * B * T + b * 32 + tid] = logf(fmaxf(p, 1e-9f));
    }
  }
}

extern "C" void kernel_launch(void* const* d_in, const int* in_sizes, int n_in,
                              void* d_out, int out_size, void* d_ws, size_t ws_size,
                              hipStream_t stream) {
  const int* tables   = (const int*)d_in[0];
  const int* sigma    = (const int*)d_in[1];
  const int* x        = (const int*)d_in[2];
  const int* base_obs = (const int*)d_in[3];
  const float* W1 = (const float*)d_in[4];
  const float* b1 = (const float*)d_in[5];
  const float* W2 = (const float*)d_in[6];
  const float* b2 = (const float*)d_in[7];
  const int* msteps = (const int*)d_in[8];
  float* out = (float*)d_out;

  const int B = in_sizes[2];
  const int N = in_sizes[1] / B;
  const int V = in_sizes[0] / (B * N);

  sim_kernel<<<dim3(B), dim3(1024), 0, stream>>>(
      tables, sigma, x, base_obs, W1, b1, W2, b2, msteps, out, B, V, N);
}